// Round 2
// baseline (1498.591 us; speedup 1.0000x reference)
//
#include <hip/hip_runtime.h>
#include <math.h>

#define S0 32
#define NRBF 16
#define NA 32
#define NB 16
#define MDIM 80           // NA + 3*NB
#define NELEM 118
#define WS_J_STRIDE 1540  // 32*48 + 4 pad -> lanes with different j hit different bank quads

// ---------------- Kernel 1: node features ----------------
__global__ void k_node_feat(const float* __restrict__ elem_id,
                            const float* __restrict__ charge,
                            const float* __restrict__ emb,
                            const float* __restrict__ Wfeat,
                            float* __restrict__ node_feat, int n) {
    int i = blockIdx.x * blockDim.x + threadIdx.x;
    if (i >= n) return;
    const float2* row = (const float2*)(elem_id + (size_t)i * NELEM);
    float best = -1e30f;
    int bi = 0;
    // 118 = 59 float2 (rows are 472B -> 8B aligned)
    for (int c = 0; c < NELEM / 2; ++c) {
        float2 v = row[c];
        if (v.x > best) { best = v.x; bi = 2 * c; }
        if (v.y > best) { best = v.y; bi = 2 * c + 1; }
    }
    float ns[11];
#pragma unroll
    for (int c = 0; c < 10; ++c) ns[c] = emb[bi * 10 + c];
    ns[10] = charge[i];
    float out[S0];
#pragma unroll
    for (int k = 0; k < S0; ++k) out[k] = 0.f;
    for (int c = 0; c < 11; ++c) {
        float f = ns[c];
#pragma unroll
        for (int k = 0; k < S0; ++k) out[k] = fmaf(f, Wfeat[c * S0 + k], out[k]);
    }
    float4* o = (float4*)(node_feat + (size_t)i * S0);
#pragma unroll
    for (int q = 0; q < S0 / 4; ++q)
        o[q] = make_float4(out[4 * q], out[4 * q + 1], out[4 * q + 2], out[4 * q + 3]);
}

// ---------------- Kernel 2: per-edge tensor product + atomic scatter ----------------
__global__ void __launch_bounds__(256)
k_edges(const float* __restrict__ pos,
        const int* __restrict__ center_idx,
        const int* __restrict__ edge_center,
        const int* __restrict__ edge_env,
        const float* __restrict__ Ws,   // (32,16,48)
        const float* __restrict__ Wv,   // (32,16)
        const float* __restrict__ node_feat,
        float* __restrict__ sums,       // (NC,80)
        float* __restrict__ cnt,        // (NC)
        int nE) {
    __shared__ float WsL[NRBF * WS_J_STRIDE];  // 98,560 B, layout [j][i][k] padded
    __shared__ float WvL[S0 * NB];             // 2 KB

    int tid = threadIdx.x;
    for (int t = tid; t < NRBF * S0 * 48; t += blockDim.x) {
        int j = t / (S0 * 48);
        int r = t - j * (S0 * 48);
        int i = r / 48;
        int k = r - i * 48;
        WsL[j * WS_J_STRIDE + r] = Ws[(i * NRBF + j) * 48 + k];
    }
    for (int t = tid; t < S0 * NB; t += blockDim.x) WvL[t] = Wv[t];
    __syncthreads();

    int e = blockIdx.x * blockDim.x + tid;
    if (e >= nE) return;

    int ec = edge_center[e];
    int en = edge_env[e];
    int gc = center_idx[ec];

    float px = pos[3 * (size_t)gc + 0] - pos[3 * (size_t)en + 0];
    float py = pos[3 * (size_t)gc + 1] - pos[3 * (size_t)en + 1];
    float pz = pos[3 * (size_t)gc + 2] - pos[3 * (size_t)en + 2];
    float d = sqrtf(px * px + py * py + pz * pz) + 1e-8f;

    // cosine soft-one-hot: at most 2 active channels
    const float inv_step = (float)(NRBF + 1) / 5.0f;  // 17/5
    float u = d * inv_step;
    float fm0 = floorf(u);
    int m0 = (int)fm0;
    float f0 = u - fm0;                       // [0,1)
    float t0 = 0.5f * (float)M_PI * f0;
    float r0 = cosf(t0);                      // channel j0 = m0-1 (diff = f0)
    float r1 = sinf(t0);                      // channel j1 = m0   (diff = f0-1)
    int j0 = m0 - 1;
    int j1 = m0;
    if (j0 < 0 || j0 >= NRBF) { j0 = 0; r0 = 0.f; }
    if (j1 < 0 || j1 >= NRBF) { j1 = 0; r1 = 0.f; }

    // gather h = node_feat[en]
    float h[S0];
    {
        const float4* hp = (const float4*)(node_feat + (size_t)en * S0);
#pragma unroll
        for (int q = 0; q < S0 / 4; ++q) {
            float4 t = hp[q];
            h[4 * q + 0] = t.x; h[4 * q + 1] = t.y; h[4 * q + 2] = t.z; h[4 * q + 3] = t.w;
        }
    }

    // s_k = sum_{p in {j0,j1}} rbf_p * sum_i h_i WsL[p][i][k]
    float acc[48];
#pragma unroll
    for (int k = 0; k < 48; ++k) acc[k] = 0.f;

#pragma unroll
    for (int p = 0; p < 2; ++p) {
        int base = (p == 0 ? j0 : j1) * WS_J_STRIDE;
        float rb = (p == 0 ? r0 : r1);
#pragma unroll 4
        for (int i = 0; i < S0; ++i) {
            float f = rb * h[i];
            const float4* w4 = (const float4*)(WsL + base + i * 48);
#pragma unroll
            for (int q = 0; q < 12; ++q) {
                float4 w = w4[q];
                acc[4 * q + 0] = fmaf(f, w.x, acc[4 * q + 0]);
                acc[4 * q + 1] = fmaf(f, w.y, acc[4 * q + 1]);
                acc[4 * q + 2] = fmaf(f, w.z, acc[4 * q + 2]);
                acc[4 * q + 3] = fmaf(f, w.w, acc[4 * q + 3]);
            }
        }
    }

    // hv_k = sum_i h_i Wv[i][k]  (uniform LDS broadcast reads)
    float hv[NB];
#pragma unroll
    for (int k = 0; k < NB; ++k) hv[k] = 0.f;
#pragma unroll 4
    for (int i = 0; i < S0; ++i) {
        float f = h[i];
        const float4* wr = (const float4*)(WvL + i * NB);
#pragma unroll
        for (int q = 0; q < NB / 4; ++q) {
            float4 w = wr[q];
            hv[4 * q + 0] = fmaf(f, w.x, hv[4 * q + 0]);
            hv[4 * q + 1] = fmaf(f, w.y, hv[4 * q + 1]);
            hv[4 * q + 2] = fmaf(f, w.z, hv[4 * q + 2]);
            hv[4 * q + 3] = fmaf(f, w.w, hv[4 * q + 3]);
        }
    }

    const float inv_s = 0.04419417382415922f;  // 1/sqrt(512)
    const float inv_v = 0.17677669529663687f;  // 1/sqrt(32)
    float* dst = sums + (size_t)ec * MDIM;

#pragma unroll
    for (int k = 0; k < NA; ++k) {
        float s = acc[k] * inv_s;
        float sg = 1.f / (1.f + expf(-s));
        unsafeAtomicAdd(dst + k, s * sg);  // silu
    }
    float ys = 1.7320508075688772f / d;  // sqrt(3)/d
    float Yx = ys * px, Yy = ys * py, Yz = ys * pz;
#pragma unroll
    for (int k = 0; k < NB; ++k) {
        float s = acc[NA + k] * inv_s;
        float g = 1.f / (1.f + expf(-s));
        float vv = hv[k] * inv_v * g;
        unsafeAtomicAdd(dst + NA + 3 * k + 0, vv * Yx);
        unsafeAtomicAdd(dst + NA + 3 * k + 1, vv * Yy);
        unsafeAtomicAdd(dst + NA + 3 * k + 2, vv * Yz);
    }
    unsafeAtomicAdd(cnt + ec, 1.0f);
}

// ---------------- Kernel 3: finalize ----------------
__global__ void k_final(const float* __restrict__ sums, const float* __restrict__ cnt,
                        const float* __restrict__ node_feat, const int* __restrict__ center_idx,
                        float* __restrict__ out, int nc) {
    int t = blockIdx.x * blockDim.x + threadIdx.x;
    int nScalar = nc * 64;
    int total = nScalar + nc * 48;
    if (t >= total) return;
    if (t < nScalar) {
        int c = t >> 6;
        int u = t & 63;
        float val;
        if (u < S0) {
            val = node_feat[(size_t)center_idx[c] * S0 + u];
        } else {
            float ct = fmaxf(cnt[c], 1.f);
            val = sums[(size_t)c * MDIM + (u - S0)] / ct;
        }
        out[t] = val;
    } else {
        int t2 = t - nScalar;
        int c = t2 / 48;
        int u = t2 - c * 48;
        float ct = fmaxf(cnt[c], 1.f);
        out[t] = sums[(size_t)c * MDIM + NA + u] / ct;
    }
}

extern "C" void kernel_launch(void* const* d_in, const int* in_sizes, int n_in,
                              void* d_out, int out_size, void* d_ws, size_t ws_size,
                              hipStream_t stream) {
    const float* pos        = (const float*)d_in[0];
    const float* elem_id    = (const float*)d_in[1];
    const float* charge     = (const float*)d_in[2];
    const int*   center_idx = (const int*)d_in[3];
    const int*   edge_center= (const int*)d_in[4];
    const int*   edge_env   = (const int*)d_in[5];
    const float* emb        = (const float*)d_in[6];
    const float* Wfeat      = (const float*)d_in[7];
    const float* Ws         = (const float*)d_in[8];
    const float* Wv         = (const float*)d_in[9];

    int nN = in_sizes[0] / 3;
    int nC = in_sizes[3];
    int nE = in_sizes[4];

    float* node_feat = (float*)d_ws;
    float* sums = node_feat + (size_t)nN * S0;
    float* cntp = sums + (size_t)nC * MDIM;

    hipMemsetAsync(sums, 0, (size_t)(nC * MDIM + nC) * sizeof(float), stream);
    k_node_feat<<<(nN + 255) / 256, 256, 0, stream>>>(elem_id, charge, emb, Wfeat, node_feat, nN);
    k_edges<<<(nE + 255) / 256, 256, 0, stream>>>(pos, center_idx, edge_center, edge_env,
                                                  Ws, Wv, node_feat, sums, cntp, nE);
    k_final<<<(nC * 112 + 255) / 256, 256, 0, stream>>>(sums, cntp, node_feat, center_idx,
                                                        (float*)d_out, nC);
}

// Round 4
// 248.903 us; speedup vs baseline: 6.0208x; 6.0208x over previous
//
#include <hip/hip_runtime.h>
#include <math.h>

#define S0 32
#define NRBF 16
#define NA 32
#define NB 16
#define MDIM 80            // NA + 3*NB
#define NELEM 118
#define CAP 96             // bucket capacity per center (Poisson(32): P(>96) ~ 1e-18)
#define WS_J_STRIDE 1544   // ushorts per j-row: 32*48 + 8 pad -> j-rows land on distinct bank quads

__device__ inline unsigned short f2bf(float a) {
    unsigned u = __float_as_uint(a);
    return (unsigned short)((u + 0x7fffu + ((u >> 16) & 1u)) >> 16);
}
__device__ inline unsigned pack_bf2(float a, float b) {
    return (unsigned)f2bf(a) | ((unsigned)f2bf(b) << 16);
}
__device__ inline float bf2f(unsigned short u) {
    return __uint_as_float(((unsigned)u) << 16);
}

// ---------------- Kernel 1: node features (LDS-staged coalesced reads) ----------------
__global__ void __launch_bounds__(256)
k_node_feat(const float* __restrict__ elem_id,
            const float* __restrict__ charge,
            const float* __restrict__ emb,
            const float* __restrict__ Wfeat,
            float* __restrict__ node_feat, int n) {
    __shared__ float rows[64 * 121];   // stride 121 (odd mod 32) -> conflict-free row reads
    __shared__ float WfL[11 * S0];
    int tid = threadIdx.x;
    int blockBase = blockIdx.x * 64;
    int nRows = n - blockBase; if (nRows > 64) nRows = 64;
    if (nRows <= 0) return;
    int totF = nRows * NELEM;
    const float* src = elem_id + (size_t)blockBase * NELEM;
    for (int t = tid; t < totF; t += 256) {
        int r = t / NELEM, c = t - r * NELEM;
        rows[r * 121 + c] = src[t];           // global read fully coalesced
    }
    for (int t = tid; t < 11 * S0; t += 256) WfL[t] = Wfeat[t];
    __syncthreads();
    if (tid >= nRows) return;
    int i = blockBase + tid;
    const float* myrow = rows + tid * 121;
    float best = -1e30f; int bi = 0;
    for (int c = 0; c < NELEM; ++c) {
        float v = myrow[c];
        if (v > best) { best = v; bi = c; }
    }
    float ns[11];
#pragma unroll
    for (int c = 0; c < 10; ++c) ns[c] = emb[bi * 10 + c];
    ns[10] = charge[i];
    float out[S0];
#pragma unroll
    for (int k = 0; k < S0; ++k) out[k] = 0.f;
#pragma unroll
    for (int c = 0; c < 11; ++c) {
        float f = ns[c];
#pragma unroll
        for (int k = 0; k < S0; ++k) out[k] = fmaf(f, WfL[c * S0 + k], out[k]);
    }
    float4* o = (float4*)(node_feat + (size_t)i * S0);
#pragma unroll
    for (int q = 0; q < S0 / 4; ++q)
        o[q] = make_float4(out[4 * q], out[4 * q + 1], out[4 * q + 2], out[4 * q + 3]);
}

// ---------------- Kernel 2: bucket fill (CSR-lite) ----------------
__global__ void k_fill(const int* __restrict__ edge_center,
                       int* __restrict__ cnt_int, int* __restrict__ bucket, int nE) {
    int e = blockIdx.x * blockDim.x + threadIdx.x;
    if (e >= nE) return;
    int ec = edge_center[e];
    int slot = atomicAdd(&cnt_int[ec], 1);
    if (slot < CAP) bucket[(size_t)ec * CAP + slot] = e;
}

// ---------------- Kernel 3: per-edge tensor product -> bf16 m[80], no atomics ----------------
__global__ void __launch_bounds__(256, 3)
k_edges(const float* __restrict__ pos,
        const int* __restrict__ center_idx,
        const int* __restrict__ edge_center,
        const int* __restrict__ edge_env,
        const float* __restrict__ Ws,   // (32,16,48) fp32
        const float* __restrict__ Wv,   // (32,16) fp32
        const float* __restrict__ node_feat,
        uint4* __restrict__ edge_m,     // (E,80) bf16 packed as 10 uint4/edge
        int nE) {
    __shared__ unsigned short WsL16[NRBF * WS_J_STRIDE];  // 49,408 B, [j][i][k] bf16
    __shared__ float WvL[S0 * NB];                        // 2 KB

    int tid = threadIdx.x;
    // stage Ws -> bf16 LDS, global reads coalesced over the source layout
    for (int t = tid; t < S0 * NRBF * 48; t += 256) {
        int i = t / (NRBF * 48);
        int r = t - i * (NRBF * 48);
        int j = r / 48;
        int k = r - j * 48;
        WsL16[j * WS_J_STRIDE + i * 48 + k] = f2bf(Ws[t]);
    }
    for (int t = tid; t < S0 * NB; t += 256) WvL[t] = Wv[t];
    __syncthreads();

    int e = blockIdx.x * blockDim.x + tid;
    if (e >= nE) return;

    int ec = edge_center[e];
    int en = edge_env[e];
    int gc = center_idx[ec];

    float px = pos[3 * (size_t)gc + 0] - pos[3 * (size_t)en + 0];
    float py = pos[3 * (size_t)gc + 1] - pos[3 * (size_t)en + 1];
    float pz = pos[3 * (size_t)gc + 2] - pos[3 * (size_t)en + 2];
    float d = sqrtf(px * px + py * py + pz * pz) + 1e-8f;

    // cosine soft-one-hot: at most 2 active channels
    const float inv_step = (float)(NRBF + 1) / 5.0f;  // 17/5
    float u = d * inv_step;
    float fm0 = floorf(u);
    int m0 = (int)fm0;
    float f0 = u - fm0;
    float t0 = 0.5f * (float)M_PI * f0;
    float r0 = cosf(t0);   // channel j0 = m0-1
    float r1 = sinf(t0);   // channel j1 = m0
    int j0 = m0 - 1, j1 = m0;
    if (j0 < 0 || j0 >= NRBF) { j0 = 0; r0 = 0.f; }
    if (j1 < 0 || j1 >= NRBF) { j1 = 0; r1 = 0.f; }

    float h[S0];
    {
        const float4* hp = (const float4*)(node_feat + (size_t)en * S0);
#pragma unroll
        for (int q = 0; q < S0 / 4; ++q) {
            float4 t = hp[q];
            h[4 * q + 0] = t.x; h[4 * q + 1] = t.y; h[4 * q + 2] = t.z; h[4 * q + 3] = t.w;
        }
    }

    float acc[48];
#pragma unroll
    for (int k = 0; k < 48; ++k) acc[k] = 0.f;

    const uint4* WsQ = (const uint4*)WsL16;   // j-row = 193 uint4
#pragma unroll
    for (int p = 0; p < 2; ++p) {
        const uint4* wp = WsQ + (p == 0 ? j0 : j1) * 193;
        float rb = (p == 0 ? r0 : r1);
#pragma unroll 4
        for (int i = 0; i < S0; ++i) {
            float f = rb * h[i];
            const uint4* w4 = wp + i * 6;
#pragma unroll
            for (int q = 0; q < 6; ++q) {
                uint4 w = w4[q];
                int kb = q * 8;
                acc[kb + 0] = fmaf(f, __uint_as_float(w.x << 16), acc[kb + 0]);
                acc[kb + 1] = fmaf(f, __uint_as_float(w.x & 0xffff0000u), acc[kb + 1]);
                acc[kb + 2] = fmaf(f, __uint_as_float(w.y << 16), acc[kb + 2]);
                acc[kb + 3] = fmaf(f, __uint_as_float(w.y & 0xffff0000u), acc[kb + 3]);
                acc[kb + 4] = fmaf(f, __uint_as_float(w.z << 16), acc[kb + 4]);
                acc[kb + 5] = fmaf(f, __uint_as_float(w.z & 0xffff0000u), acc[kb + 5]);
                acc[kb + 6] = fmaf(f, __uint_as_float(w.w << 16), acc[kb + 6]);
                acc[kb + 7] = fmaf(f, __uint_as_float(w.w & 0xffff0000u), acc[kb + 7]);
            }
        }
    }

    // hv_k = sum_i h_i Wv[i][k]  (uniform LDS broadcast reads)
    float hv[NB];
#pragma unroll
    for (int k = 0; k < NB; ++k) hv[k] = 0.f;
#pragma unroll 4
    for (int i = 0; i < S0; ++i) {
        float f = h[i];
        const float4* wr = (const float4*)(WvL + i * NB);
#pragma unroll
        for (int q = 0; q < NB / 4; ++q) {
            float4 w = wr[q];
            hv[4 * q + 0] = fmaf(f, w.x, hv[4 * q + 0]);
            hv[4 * q + 1] = fmaf(f, w.y, hv[4 * q + 1]);
            hv[4 * q + 2] = fmaf(f, w.z, hv[4 * q + 2]);
            hv[4 * q + 3] = fmaf(f, w.w, hv[4 * q + 3]);
        }
    }

    const float inv_s = 0.04419417382415922f;  // 1/sqrt(512)
    const float inv_v = 0.17677669529663687f;  // 1/sqrt(32)
    float m[MDIM];
#pragma unroll
    for (int k = 0; k < NA; ++k) {
        float s = acc[k] * inv_s;
        float sg = 1.f / (1.f + expf(-s));
        m[k] = s * sg;
    }
    float ys = 1.7320508075688772f / d;
    float Yx = ys * px, Yy = ys * py, Yz = ys * pz;
#pragma unroll
    for (int k = 0; k < NB; ++k) {
        float s = acc[NA + k] * inv_s;
        float g = 1.f / (1.f + expf(-s));
        float vv = hv[k] * inv_v * g;
        m[NA + 3 * k + 0] = vv * Yx;
        m[NA + 3 * k + 1] = vv * Yy;
        m[NA + 3 * k + 2] = vv * Yz;
    }

    uint4* dst = edge_m + (size_t)e * 10;
#pragma unroll
    for (int q = 0; q < 10; ++q) {
        uint4 w;
        w.x = pack_bf2(m[8 * q + 0], m[8 * q + 1]);
        w.y = pack_bf2(m[8 * q + 2], m[8 * q + 3]);
        w.z = pack_bf2(m[8 * q + 4], m[8 * q + 5]);
        w.w = pack_bf2(m[8 * q + 6], m[8 * q + 7]);
        dst[q] = w;
    }
}

// ---------------- Kernel 4: per-center reduce + finalize ----------------
__global__ void __launch_bounds__(128)
k_centers(const unsigned short* __restrict__ edge_m,
          const int* __restrict__ bucket, const int* __restrict__ cnt_int,
          const float* __restrict__ node_feat, const int* __restrict__ center_idx,
          float* __restrict__ out, int nc) {
    int c = blockIdx.x;
    if (c >= nc) return;
    int lane = threadIdx.x;
    int n = cnt_int[c];
    int nl = n > CAP ? CAP : n;
    if (lane < MDIM) {
        const int* bk = bucket + (size_t)c * CAP;
        float acc = 0.f;
        int s = 0;
        for (; s + 4 <= nl; s += 4) {
            int e0 = bk[s], e1 = bk[s + 1], e2 = bk[s + 2], e3 = bk[s + 3];
            float a0 = bf2f(edge_m[(size_t)e0 * MDIM + lane]);
            float a1 = bf2f(edge_m[(size_t)e1 * MDIM + lane]);
            float a2 = bf2f(edge_m[(size_t)e2 * MDIM + lane]);
            float a3 = bf2f(edge_m[(size_t)e3 * MDIM + lane]);
            acc += (a0 + a1) + (a2 + a3);
        }
        for (; s < nl; ++s) acc += bf2f(edge_m[(size_t)bk[s] * MDIM + lane]);
        float agg = acc / fmaxf((float)n, 1.f);
        if (lane < NA) out[(size_t)c * 64 + S0 + lane] = agg;
        else out[(size_t)nc * 64 + (size_t)c * 48 + (lane - NA)] = agg;
    } else if (lane < MDIM + S0) {
        int t = lane - MDIM;
        out[(size_t)c * 64 + t] = node_feat[(size_t)center_idx[c] * S0 + t];
    }
}

extern "C" void kernel_launch(void* const* d_in, const int* in_sizes, int n_in,
                              void* d_out, int out_size, void* d_ws, size_t ws_size,
                              hipStream_t stream) {
    const float* pos        = (const float*)d_in[0];
    const float* elem_id    = (const float*)d_in[1];
    const float* charge     = (const float*)d_in[2];
    const int*   center_idx = (const int*)d_in[3];
    const int*   edge_center= (const int*)d_in[4];
    const int*   edge_env   = (const int*)d_in[5];
    const float* emb        = (const float*)d_in[6];
    const float* Wfeat      = (const float*)d_in[7];
    const float* Ws         = (const float*)d_in[8];
    const float* Wv         = (const float*)d_in[9];

    int nN = in_sizes[0] / 3;
    int nC = in_sizes[3];
    int nE = in_sizes[4];

    // ws layout: edge_m bf16 (E*80*2B) | node_feat f32 (nN*32*4B) | bucket int (nC*96*4B) | cnt int (nC*4B)
    char* wsb = (char*)d_ws;
    uint4* edge_m = (uint4*)wsb;
    size_t off = (size_t)nE * MDIM * 2;
    off = (off + 15) & ~(size_t)15;
    float* node_feat = (float*)(wsb + off);
    off += (size_t)nN * S0 * 4;
    int* bucket = (int*)(wsb + off);
    off += (size_t)nC * CAP * 4;
    int* cnt_int = (int*)(wsb + off);

    hipMemsetAsync(cnt_int, 0, (size_t)nC * 4, stream);
    k_node_feat<<<(nN + 63) / 64, 256, 0, stream>>>(elem_id, charge, emb, Wfeat, node_feat, nN);
    k_fill<<<(nE + 255) / 256, 256, 0, stream>>>(edge_center, cnt_int, bucket, nE);
    k_edges<<<(nE + 255) / 256, 256, 0, stream>>>(pos, center_idx, edge_center, edge_env,
                                                  Ws, Wv, node_feat, edge_m, nE);
    k_centers<<<nC, 128, 0, stream>>>((const unsigned short*)edge_m, bucket, cnt_int,
                                      node_feat, center_idx, (float*)d_out, nC);
}